// Round 2
// baseline (2196.667 us; speedup 1.0000x reference)
//
#include <hip/hip_runtime.h>
#include <hip/hip_bf16.h>
#include <math.h>

using bf16 = __hip_bfloat16;
typedef __attribute__((ext_vector_type(8))) short s8v;
typedef __attribute__((ext_vector_type(4))) float f4v;

#define MTOT 65536   // B*T
#define TLEN 2048
#define NCHUNK 16
#define TCH 128

__device__ __forceinline__ float b2f(bf16 x) { return __bfloat162float(x); }
__device__ __forceinline__ bf16 f2b(float x) { return __float2bfloat16(x); }
__device__ __forceinline__ float bits2f(unsigned short u) {
    unsigned int x = ((unsigned int)u) << 16; float f; __builtin_memcpy(&f, &x, 4); return f;
}
__device__ __forceinline__ unsigned short f2bits(float x) {
    bf16 h = f2b(x); unsigned short u; __builtin_memcpy(&u, &h, 2); return u;
}

// flagged load: f32 buffer if f!=0 else bf16 buffer
__device__ __forceinline__ float ldf(const void* p, size_t i, int f) {
    return f ? ((const float*)p)[i] : b2f(((const bf16*)p)[i]);
}

__device__ __forceinline__ void ld_g2l(const void* g, void* l) {
    __builtin_amdgcn_global_load_lds(
        (const __attribute__((address_space(1))) void*)g,
        (__attribute__((address_space(3))) void*)l,
        16, 0, 0);
}

// ---------------- dtype detection ----------------
__global__ void detect_k(const unsigned short* __restrict__ x, int* __restrict__ flag) {
    int tid = threadIdx.x;
    int cnt = 0;
    for (int i = tid; i < 8192; i += 256) {
        int e = (x[i] >> 7) & 0xFF;
        if (e == 0 || e == 0xFF) cnt++;
    }
    __shared__ int red[256];
    red[tid] = cnt;
    __syncthreads();
    for (int s = 128; s > 0; s >>= 1) {
        if (tid < s) red[tid] += red[tid + s];
        __syncthreads();
    }
    if (tid == 0) flag[0] = (red[0] >= 2) ? 1 : 0;
}

__global__ void cvt_k(const void* __restrict__ src, bf16* __restrict__ dst, int n,
                      const int* __restrict__ flag) {
    int f = *flag;
    int i = blockIdx.x * 256 + threadIdx.x;
    if (i < n) dst[i] = f2b(ldf(src, i, f));
}

__global__ void lamgam_k(const void* __restrict__ nu, const void* __restrict__ th,
                         float* __restrict__ lamb, float* __restrict__ gamt,
                         const int* __restrict__ flag) {
    int f = *flag;
    int g = blockIdx.x * 256 + threadIdx.x;  // 1536
    float nl = ldf(nu, g, f), tl = ldf(th, g, f);
    float mag = expf(-expf(nl));
    float ang = expf(tl);
    lamb[g * 2] = mag * cosf(ang);
    lamb[g * 2 + 1] = mag * sinf(ang);
    gamt[g] = sqrtf(fmaxf(1.f - mag * mag, 1e-12f));
}

// =====================================================================
// Persistent weights-resident streaming GEMM.
// out[m,n] = sum_k A[m,k]*W[n,k] (+epilogue)
// 256 blocks exactly (1/CU, ~130KB LDS). Each block: one N-panel (BN cols,
// W panel resident in LDS), TPB M-tiles of 128 rows, A streamed in 16KB
// chunks (128 rows x 64 k) through a 4-buffer ring with counted vmcnt(8)
// (2 chunks always in flight). bn-siblings share an XCD for L2 reuse of A.
// EPI 1: +bias -> outB & outB2, + BN-stats partials      (encoder)
// EPI 2: +Dv[n]*(a[n]*aux+c[n]) -> bf16                  (LRU C-out)
// EPI 5: v+bias+aux[m,n] -> bf16, + BN-stats partials    (W2 + residual)
// EPI 6: +fbias[n] (fp32) -> bf16                        (Bu, BN folded)
// EPI 7: (v+b1v)*sigmoid(g+b1g) -> bf16                  (fused GLU; W2nd panel)
// =====================================================================
template<int BN, int H, int LOG2H, int NBN, int TPB, int EPI>
__global__ __launch_bounds__(256, 1)
void gemm_rs(const bf16* __restrict__ A, int lda,
             const bf16* __restrict__ W, int K,
             bf16* __restrict__ outB, bf16* __restrict__ outB2, int ldo,
             const bf16* __restrict__ bias,
             const bf16* __restrict__ Dv, const bf16* __restrict__ aux,
             const float* __restrict__ fstats, float* __restrict__ spart)
{
    constexpr int JN  = (BN == 128) ? 4 : 2;
    constexpr int NSW = (BN == 128) ? 64 : 32;
    constexpr bool GLU = (EPI == 7);
    constexpr bool STATS = (EPI == 1 || EPI == 5);
    constexpr int WCH = BN * 128;            // bytes per W k-chunk in LDS
    constexpr int NC = TPB * H;              // chunks per block

    __shared__ __align__(16) char WsL[H * WCH * (GLU ? 2 : 1)];
    __shared__ __align__(16) char AbL[4 * 16384];
    __shared__ float sred[512];

    const int tid = threadIdx.x;
    const int lane = tid & 63, wv = tid >> 6;
    const int wm = wv >> 1, wn = wv & 1;
    const int quad = lane >> 4, cl = lane & 15;
    const int rsub = lane >> 3;
    const int swz = ((lane & 7) ^ rsub) * 16;

    // job mapping: bn-siblings share XCD (blockIdx == same mod 8)
    const int b = blockIdx.x;
    const int xcd = b & 7;
    const int bn = (b >> 3) & (NBN - 1);
    const int q = b / (8 * NBN);
    const int bm0 = (q * 8 + xcd) * TPB;

    auto stageA = [&](int c) {
        const int t = c >> LOG2H, kc = c & (H - 1);
        const char* g = (const char*)A + (size_t)(bm0 + t) * 128 * ((size_t)lda * 2) + kc * 128;
        char* l = AbL + (c & 3) * 16384;
#pragma unroll
        for (int it = 0; it < 4; ++it) {
            int sg = it * 4 + wv;
            ld_g2l(g + (size_t)(sg * 8 + rsub) * ((size_t)lda * 2) + swz, l + sg * 1024);
        }
    };
    auto stageW = [&](const bf16* Wb, char* lb) {
        constexpr int NIT = (BN / 8) / 4;
#pragma unroll
        for (int kc = 0; kc < H; ++kc) {
#pragma unroll
            for (int it = 0; it < NIT; ++it) {
                int sg = it * 4 + wv;
                ld_g2l((const char*)Wb + (size_t)(sg * 8 + rsub) * ((size_t)K * 2) + kc * 128 + swz,
                       lb + kc * WCH + sg * 1024);
            }
        }
    };

    stageW(W + (size_t)(bn * BN) * K, WsL);
    if (GLU) stageW(W + (size_t)(512 + bn * 64) * K, WsL + H * WCH);
    stageA(0); stageA(1); stageA(2);

    f4v acc[4][JN];
    f4v accg[4][JN];
#pragma unroll
    for (int i = 0; i < 4; i++)
#pragma unroll
        for (int j = 0; j < JN; j++) {
            acc[i][j] = (f4v){0.f, 0.f, 0.f, 0.f};
            if (GLU) accg[i][j] = (f4v){0.f, 0.f, 0.f, 0.f};
        }

    int tile = 0;
    const size_t ld = (size_t)ldo;
#pragma unroll 1
    for (int c = 0; c < NC; ++c) {
        const int rem = NC - 1 - c;
        if (rem >= 2)      { asm volatile("s_waitcnt vmcnt(8)" ::: "memory"); }
        else if (rem == 1) { asm volatile("s_waitcnt vmcnt(4)" ::: "memory"); }
        else               { asm volatile("s_waitcnt vmcnt(0)" ::: "memory"); }
        __builtin_amdgcn_s_barrier();
        if (c + 3 < NC) stageA(c + 3);

        const int kc = c & (H - 1);
        const char* Ab = AbL + (c & 3) * 16384;
        const char* Wc = WsL + kc * WCH;
#pragma unroll
        for (int kk = 0; kk < 2; ++kk) {
            s8v af[4];
#pragma unroll
            for (int i = 0; i < 4; i++) {
                int rr = wm * 64 + i * 16 + cl;
                af[i] = *(const s8v*)(Ab + rr * 128 + (((kk * 4 + quad) ^ (rr & 7)) * 16));
            }
            s8v bf_[JN];
#pragma unroll
            for (int j = 0; j < JN; j++) {
                int rn = wn * NSW + j * 16 + cl;
                bf_[j] = *(const s8v*)(Wc + rn * 128 + (((kk * 4 + quad) ^ (rn & 7)) * 16));
            }
#pragma unroll
            for (int i = 0; i < 4; i++)
#pragma unroll
                for (int j = 0; j < JN; j++)
                    acc[i][j] = __builtin_amdgcn_mfma_f32_16x16x32_bf16(af[i], bf_[j], acc[i][j], 0, 0, 0);
            if constexpr (GLU) {
                s8v bg[JN];
#pragma unroll
                for (int j = 0; j < JN; j++) {
                    int rn = wn * NSW + j * 16 + cl;
                    bg[j] = *(const s8v*)(WsL + H * WCH + kc * WCH + rn * 128 + (((kk * 4 + quad) ^ (rn & 7)) * 16));
                }
#pragma unroll
                for (int i = 0; i < 4; i++)
#pragma unroll
                    for (int j = 0; j < JN; j++)
                        accg[i][j] = __builtin_amdgcn_mfma_f32_16x16x32_bf16(af[i], bg[j], accg[i][j], 0, 0, 0);
            }
        }

        if (kc == H - 1) {
            // ---- epilogue for this tile ----
            const int bm = bm0 + tile;
#pragma unroll
            for (int j = 0; j < JN; j++) {
                float ss = 0.f, ss2 = 0.f;
                const int n = bn * BN + wn * NSW + j * 16 + cl;
#pragma unroll
                for (int i = 0; i < 4; i++) {
#pragma unroll
                    for (int r4 = 0; r4 < 4; r4++) {
                        int m = bm * 128 + wm * 64 + i * 16 + quad * 4 + r4;
                        size_t idx = (size_t)m * ld + n;
                        float v = acc[i][j][r4];
                        if (EPI == 1) {
                            v += b2f(bias[n]);
                            outB[idx] = f2b(v);
                            outB2[idx] = f2b(v);
                        } else if (EPI == 2) {
                            v += b2f(Dv[n]) * (fstats[n] * b2f(aux[idx]) + fstats[256 + n]);
                            outB[idx] = f2b(v);
                        } else if (EPI == 5) {
                            v += b2f(bias[n]) + b2f(aux[idx]);
                            outB[idx] = f2b(v);
                        } else if (EPI == 6) {
                            v += fstats[n];
                            outB[idx] = f2b(v);
                        } else if (EPI == 7) {
                            float g = accg[i][j][r4] + b2f(bias[512 + n]);
                            v += b2f(bias[n]);
                            outB[idx] = f2b(v * (1.f / (1.f + expf(-g))));
                        }
                        if (STATS) { ss += v; ss2 += v * v; }
                    }
                }
                if (STATS) {
                    ss += __shfl_xor(ss, 16);  ss += __shfl_xor(ss, 32);
                    ss2 += __shfl_xor(ss2, 16); ss2 += __shfl_xor(ss2, 32);
                    if (lane < 16) {
                        sred[(wv * JN + j) * 16 + cl] = ss;
                        sred[256 + (wv * JN + j) * 16 + cl] = ss2;
                    }
                }
            }
            if constexpr (STATS) {
                constexpr int HALF = 4 * JN * 16 / 2;   // 128 (BN=128) / 64 (BN=64)
                asm volatile("s_waitcnt lgkmcnt(0)" ::: "memory");
                __builtin_amdgcn_s_barrier();
                if (tid < HALF) {
                    float sv = sred[tid] + sred[HALF + tid];
                    float sv2 = sred[256 + tid] + sred[256 + HALF + tid];
                    spart[(size_t)bm * 256 + bn * BN + tid] = sv;
                    spart[131072 + (size_t)bm * 256 + bn * BN + tid] = sv2;
                }
            }
            tile++;
#pragma unroll
            for (int i = 0; i < 4; i++)
#pragma unroll
                for (int j = 0; j < JN; j++) {
                    acc[i][j] = (f4v){0.f, 0.f, 0.f, 0.f};
                    if (GLU) accg[i][j] = (f4v){0.f, 0.f, 0.f, 0.f};
                }
        }
    }
}

// ---------------- BatchNorm finish: partials -> affine tables -------------
// stats[e] = a = rsqrt(var+eps)*scale ; stats[256+e] = c = bias - mu*a
__global__ void bn_finish2(const float* __restrict__ part, float* __restrict__ stats,
                           const bf16* __restrict__ sc, const bf16* __restrict__ bi) {
    int e = blockIdx.x;   // 256
    int t = threadIdx.x;
    float s = part[(size_t)t * 256 + e] + part[(size_t)(t + 256) * 256 + e];
    float s2 = part[131072 + (size_t)t * 256 + e] + part[131072 + (size_t)(t + 256) * 256 + e];
    __shared__ float rs[256], rs2[256];
    rs[t] = s; rs2[t] = s2;
    __syncthreads();
    for (int k = 128; k > 0; k >>= 1) {
        if (t < k) { rs[t] += rs[t + k]; rs2[t] += rs2[t + k]; }
        __syncthreads();
    }
    if (t == 0) {
        float mu = rs[0] * (1.f / 65536.f);
        float var = rs2[0] * (1.f / 65536.f) - mu * mu;
        float a = rsqrtf(var + 1e-5f) * b2f(sc[e]);
        stats[e] = a;
        stats[256 + e] = b2f(bi[e]) - mu * a;
    }
}

// Bu bias from BN shift: out[n] = gamma[h] * sum_e c[e]*B_?[h,e]
__global__ void bias_bu2(const void* __restrict__ B_re, const void* __restrict__ B_im,
                         size_t off, const float* __restrict__ gam,
                         const float* __restrict__ stats,
                         float* __restrict__ out, const int* __restrict__ flag) {
    int f = *flag;
    int n = blockIdx.x;   // 512
    int h = n & 255;
    const void* src = (n < 256) ? B_re : B_im;
    int t = threadIdx.x;
    float v = stats[256 + t] * ldf(src, off + (size_t)h * 256 + t, f);
    __shared__ float rs[256];
    rs[t] = v; __syncthreads();
    for (int k = 128; k > 0; k >>= 1) {
        if (t < k) rs[t] += rs[t + k];
        __syncthreads();
    }
    if (t == 0) out[n] = rs[0] * gam[h];
}

// ---------------- LRU scan (chunked, in-place over Bu) ----------------
// bu layout: [M, 512] bf16, cols 0..255 = re, 256..511 = im
__global__ void lru_carry(const bf16* __restrict__ bu, const float* __restrict__ lam,
                          float* __restrict__ carry) {
    int gg = blockIdx.x * 256 + threadIdx.x;  // 65536 pairs
    int hp = gg & 127, c = (gg >> 7) & 15, b = gg >> 11;
    f4v lm = *(const f4v*)&lam[hp * 4];       // lr0,li0,lr1,li1
    float sr0 = 0.f, si0 = 0.f, sr1 = 0.f, si1 = 0.f;
    const bf16* p = bu + ((size_t)(b * TLEN + c * TCH)) * 512 + hp * 2;
    for (int t = 0; t < TCH; t++) {
        unsigned int cr = *(const unsigned int*)p;
        unsigned int ci = *(const unsigned int*)(p + 256);
        float ur0 = bits2f((unsigned short)cr), ur1 = bits2f((unsigned short)(cr >> 16));
        float ui0 = bits2f((unsigned short)ci), ui1 = bits2f((unsigned short)(ci >> 16));
        float nr0 = lm[0] * sr0 - lm[1] * si0 + ur0;
        si0 = lm[0] * si0 + lm[1] * sr0 + ui0; sr0 = nr0;
        float nr1 = lm[2] * sr1 - lm[3] * si1 + ur1;
        si1 = lm[2] * si1 + lm[3] * sr1 + ui1; sr1 = nr1;
        p += 512;
    }
    *(f4v*)&carry[(size_t)gg * 4] = (f4v){sr0, si0, sr1, si1};
}

__global__ void lru_prefix(const float* __restrict__ carry, float* __restrict__ pre,
                           const float* __restrict__ lam) {
    int g = blockIdx.x * 256 + threadIdx.x;  // 8192
    int h = g & 255, b = g >> 8;
    float pr = lam[h * 2], pi = lam[h * 2 + 1];  // lam^128 via 7 squarings
    for (int k = 0; k < 7; k++) { float nr = pr * pr - pi * pi; pi = 2.f * pr * pi; pr = nr; }
    float er = 0.f, ei = 0.f;
    for (int c = 0; c < NCHUNK; c++) {
        size_t idx = ((size_t)(b * NCHUNK + c) * 256 + h) * 2;
        pre[idx] = er; pre[idx + 1] = ei;
        float cr = carry[idx], ci = carry[idx + 1];
        float nr = pr * er - pi * ei + cr;
        ei = pr * ei + pi * er + ci;
        er = nr;
    }
}

__global__ void lru_final(bf16* __restrict__ bu, const float* __restrict__ pre,
                          const float* __restrict__ lam) {
    int gg = blockIdx.x * 256 + threadIdx.x;  // 65536 pairs
    int hp = gg & 127, c = (gg >> 7) & 15, b = gg >> 11;
    f4v lm = *(const f4v*)&lam[hp * 4];
    f4v st = *(const f4v*)&pre[(size_t)gg * 4];
    float sr0 = st[0], si0 = st[1], sr1 = st[2], si1 = st[3];
    bf16* p = bu + ((size_t)(b * TLEN + c * TCH)) * 512 + hp * 2;
    for (int t = 0; t < TCH; t++) {
        unsigned int cr = *(const unsigned int*)p;
        unsigned int ci = *(const unsigned int*)(p + 256);
        float ur0 = bits2f((unsigned short)cr), ur1 = bits2f((unsigned short)(cr >> 16));
        float ui0 = bits2f((unsigned short)ci), ui1 = bits2f((unsigned short)(ci >> 16));
        float nr0 = lm[0] * sr0 - lm[1] * si0 + ur0;
        si0 = lm[0] * si0 + lm[1] * sr0 + ui0; sr0 = nr0;
        float nr1 = lm[2] * sr1 - lm[3] * si1 + ur1;
        si1 = lm[2] * si1 + lm[3] * sr1 + ui1; sr1 = nr1;
        *(unsigned int*)p = (unsigned int)f2bits(sr0) | ((unsigned int)f2bits(sr1) << 16);
        *(unsigned int*)(p + 256) = (unsigned int)f2bits(si0) | ((unsigned int)f2bits(si1) << 16);
        p += 512;
    }
}

// ---------------- pooling + head ----------------
__global__ void pool_part(const bf16* __restrict__ xc, float* __restrict__ part) {
    int blk = blockIdx.x;  // 512
    int b = blk >> 4, tc = blk & 15;
    int e = threadIdx.x;
    const bf16* p = xc + ((size_t)b * TLEN + tc * TCH) * 256 + e;
    float s = 0.f;
    for (int r = 0; r < TCH; r++) { s += b2f(*p); p += 256; }
    part[(size_t)blk * 256 + e] = s;
}

__global__ void head_k(const float* __restrict__ part, const bf16* __restrict__ W_out,
                       const bf16* __restrict__ b_out, void* __restrict__ out,
                       const int* __restrict__ flag) {
    int b = blockIdx.x;
    int tid = threadIdx.x;
    __shared__ float sp[256];
    __shared__ float red[160];
    float s = 0.f;
    for (int c = 0; c < 16; c++) s += part[((size_t)(b * 16 + c)) * 256 + tid];
    sp[tid] = s * (1.f / 2048.f);
    __syncthreads();
    if (tid < 160) {
        int o = tid >> 4, sg = tid & 15;
        float a = 0.f;
        for (int e = sg; e < 256; e += 16) a += sp[e] * b2f(W_out[e * 10 + o]);
        red[tid] = a;
    }
    __syncthreads();
    if (tid < 10) {
        float acc = b2f(b_out[tid]);
        for (int sg = 0; sg < 16; sg++) acc += red[tid * 16 + sg];
        if (*flag) ((float*)out)[b * 10 + tid] = acc;
        else       ((bf16*)out)[b * 10 + tid] = f2b(acc);
    }
}

// ---------------- weight packing (flagged dtype reads) ----------------
__global__ void pack_wt_enc(const void* __restrict__ W_enc, bf16* __restrict__ out,
                            const int* __restrict__ flag) {
    int f = *flag;
    int g = blockIdx.x * 256 + threadIdx.x;  // 16384
    int n = g >> 6, k = g & 63;
    out[g] = f2b(ldf(W_enc, (size_t)k * 256 + n, f));
}

// wb[n,e] = B_?[h,e] * gamma[h] * a[e]   (BN scale folded along K)
__global__ void pack_wb(const void* __restrict__ B_re, const void* __restrict__ B_im,
                        size_t off, const float* __restrict__ gam,
                        const float* __restrict__ stats,
                        bf16* __restrict__ out, const int* __restrict__ flag) {
    int f = *flag;
    int g = blockIdx.x * 256 + threadIdx.x;  // 512*256
    int n = g >> 8, e = g & 255;
    int h = n & 255;
    const void* src = (n < 256) ? B_re : B_im;
    out[g] = f2b(ldf(src, off + (size_t)h * 256 + e, f) * gam[h] * stats[e]);
}

__global__ void pack_wc(const void* __restrict__ C_re, const void* __restrict__ C_im,
                        size_t off, bf16* __restrict__ out, const int* __restrict__ flag) {
    int f = *flag;
    int g = blockIdx.x * 256 + threadIdx.x;  // 256*512
    int e = g >> 9, k = g & 511;
    float v = (k < 256) ? ldf(C_re, off + (size_t)e * 256 + k, f)
                        : -ldf(C_im, off + (size_t)e * 256 + (k - 256), f);
    out[g] = f2b(v);
}

__global__ void pack_w1t(const void* __restrict__ W1, size_t off, bf16* __restrict__ out,
                         const int* __restrict__ flag) {
    int f = *flag;
    int g = blockIdx.x * 256 + threadIdx.x;  // 1024*256
    int n = g >> 8, k = g & 255;
    out[g] = f2b(ldf(W1, off + (size_t)k * 1024 + n, f));
}

__global__ void pack_w2t(const void* __restrict__ W2, size_t off, bf16* __restrict__ out,
                         const int* __restrict__ flag) {
    int f = *flag;
    int g = blockIdx.x * 256 + threadIdx.x;  // 256*512
    int n = g >> 9, k = g & 511;
    out[g] = f2b(ldf(W2, off + (size_t)k * 256 + n, f));
}

extern "C" void kernel_launch(void* const* d_in, const int* in_sizes, int n_in,
                              void* d_out, int out_size, void* d_ws, size_t ws_size,
                              hipStream_t stream) {
    (void)in_sizes; (void)n_in; (void)out_size; (void)ws_size;
    const void* x      = d_in[0];
    const void* W_enc  = d_in[1];
    const void* b_enc  = d_in[2];
    const void* nu_log = d_in[3];
    const void* th_log = d_in[4];
    const void* B_re   = d_in[5];
    const void* B_im   = d_in[6];
    const void* C_re   = d_in[7];
    const void* C_im   = d_in[8];
    const void* Dp     = d_in[9];
    const void* W1     = d_in[10];
    const void* b1     = d_in[11];
    const void* W2     = d_in[12];
    const void* b2     = d_in[13];
    const void* bn_s   = d_in[14];
    const void* bn_b   = d_in[15];
    const void* W_out  = d_in[16];
    const void* b_out  = d_in[17];

    // workspace layout (~173 MB)
    char* w = (char*)d_ws;
    bf16* xc  = (bf16*)w; w += (size_t)MTOT * 256 * 2;   // residual stream
    bf16* y   = (bf16*)w; w += (size_t)MTOT * 256 * 2;   // residual anchor
    bf16* hbn = (bf16*)w; w += (size_t)MTOT * 256 * 2;   // LRU out
    bf16* bu  = (bf16*)w; w += (size_t)MTOT * 512 * 2;   // Bu/hs, then GLU out
    float* stats  = (float*)w; w += 4096;                // a[256], c[256]
    float* bnpart = (float*)w; w += 1048576;             // stats partials (from GEMM epilogue)
    float* carry  = (float*)w; w += 1048576;
    float* pre    = (float*)w; w += 1048576;
    float* part   = (float*)w; w += 524288;
    float* lamb   = (float*)w; w += 12288;               // 1536*2 fp32
    float* gamt   = (float*)w; w += 6144;                // 1536 fp32
    float* bubias = (float*)w; w += 2048;                // 512 fp32
    int*   flag   = (int*)w;  w += 256;
    bf16* wt_enc = (bf16*)w; w += 32768;
    bf16* wb  = (bf16*)w; w += 262144;
    bf16* wc  = (bf16*)w; w += 262144;
    bf16* w1t = (bf16*)w; w += 524288;
    bf16* w2t = (bf16*)w; w += 262144;
    bf16* b_encb = (bf16*)w; w += 512;
    bf16* Db     = (bf16*)w; w += 3072;
    bf16* b1b    = (bf16*)w; w += 12288;
    bf16* b2b    = (bf16*)w; w += 3072;
    bf16* bnsb   = (bf16*)w; w += 3072;
    bf16* bnbb   = (bf16*)w; w += 3072;
    bf16* Woutb  = (bf16*)w; w += 5120;
    bf16* boutb  = (bf16*)w; w += 32;
    bf16* xb = bu;  // x's bf16 copy aliases bu (dead until first Bu GEMM)

    dim3 blk(256);
    detect_k<<<1, blk, 0, stream>>>((const unsigned short*)x, flag);
    cvt_k<<<16384, blk, 0, stream>>>(x, xb, 4194304, flag);
    cvt_k<<<1, blk, 0, stream>>>(b_enc, b_encb, 256, flag);
    cvt_k<<<6, blk, 0, stream>>>(Dp, Db, 1536, flag);
    cvt_k<<<24, blk, 0, stream>>>(b1, b1b, 6144, flag);
    cvt_k<<<6, blk, 0, stream>>>(b2, b2b, 1536, flag);
    cvt_k<<<6, blk, 0, stream>>>(bn_s, bnsb, 1536, flag);
    cvt_k<<<6, blk, 0, stream>>>(bn_b, bnbb, 1536, flag);
    cvt_k<<<10, blk, 0, stream>>>(W_out, Woutb, 2560, flag);
    cvt_k<<<1, blk, 0, stream>>>(b_out, boutb, 10, flag);
    lamgam_k<<<6, blk, 0, stream>>>(nu_log, th_log, lamb, gamt, flag);
    pack_wt_enc<<<64, blk, 0, stream>>>(W_enc, wt_enc, flag);

    // encoder: [M,64] @ W_enc^T + b_enc -> xc and y (+ BN stats partials)
    gemm_rs<128, 1, 0, 2, 4, 1><<<256, blk, 0, stream>>>(
        xb, 64, wt_enc, 64, xc, y, 256, b_encb, nullptr, nullptr, nullptr, bnpart);
    for (int i = 0; i < 6; ++i) {
        bn_finish2<<<256, blk, 0, stream>>>(bnpart, stats, bnsb + i * 256, bnbb + i * 256);
        pack_wb<<<512, blk, 0, stream>>>(B_re, B_im, (size_t)i * 65536, gamt + i * 256, stats, wb, flag);
        bias_bu2<<<512, blk, 0, stream>>>(B_re, B_im, (size_t)i * 65536, gamt + i * 256, stats, bubias, flag);
        // Bu = BN(xc) @ (gamma*[B_re;B_im])^T  (BN folded into weights+bias)
        gemm_rs<128, 4, 2, 4, 8, 6><<<256, blk, 0, stream>>>(
            xc, 256, wb, 256, bu, nullptr, 512, nullptr, nullptr, nullptr, bubias, nullptr);
        lru_carry<<<256, blk, 0, stream>>>(bu, lamb + i * 512, carry);
        lru_prefix<<<32, blk, 0, stream>>>(carry, pre, lamb + i * 512);
        lru_final<<<256, blk, 0, stream>>>(bu, pre, lamb + i * 512);
        pack_wc<<<512, blk, 0, stream>>>(C_re, C_im, (size_t)i * 65536, wc, flag);
        // lru_out = hs @ [C_re;-C_im]^T + D*(a*xc+c) -> hbn [M,256]
        gemm_rs<64, 8, 3, 4, 8, 2><<<256, blk, 0, stream>>>(
            bu, 512, wc, 512, hbn, nullptr, 256, nullptr, Db + i * 256, xc, stats, nullptr);
        pack_w1t<<<1024, blk, 0, stream>>>(W1, (size_t)i * 262144, w1t, flag);
        // fused GLU MLP: bu = (hbn@W1v+b1v)*sigmoid(hbn@W1g+b1g)  [M,512]
        gemm_rs<64, 4, 2, 8, 16, 7><<<256, blk, 0, stream>>>(
            hbn, 256, w1t, 256, bu, nullptr, 512, b1b + i * 1024, nullptr, nullptr, nullptr, nullptr);
        pack_w2t<<<512, blk, 0, stream>>>(W2, (size_t)i * 131072, w2t, flag);
        // xc = glu @ W2^T + b2 + y (+ BN stats partials for next layer)
        gemm_rs<64, 8, 3, 4, 8, 5><<<256, blk, 0, stream>>>(
            bu, 512, w2t, 512, xc, nullptr, 256, b2b + i * 256, nullptr, y, nullptr, bnpart);
    }
    pool_part<<<512, blk, 0, stream>>>(xc, part);
    head_k<<<32, blk, 0, stream>>>(part, Woutb, boutb, d_out, flag);
}

// Round 3
// 1716.885 us; speedup vs baseline: 1.2794x; 1.2794x over previous
//
#include <hip/hip_runtime.h>
#include <hip/hip_bf16.h>
#include <math.h>

using bf16 = __hip_bfloat16;
typedef __attribute__((ext_vector_type(8))) short s8v;
typedef __attribute__((ext_vector_type(4))) float f4v;

#define MTOT 65536   // B*T
#define TLEN 2048
#define NCHUNK 16
#define TCH 128

__device__ __forceinline__ float b2f(bf16 x) { return __bfloat162float(x); }
__device__ __forceinline__ bf16 f2b(float x) { return __float2bfloat16(x); }
__device__ __forceinline__ float bits2f(unsigned short u) {
    unsigned int x = ((unsigned int)u) << 16; float f; __builtin_memcpy(&f, &x, 4); return f;
}
__device__ __forceinline__ unsigned short f2bits(float x) {
    bf16 h = f2b(x); unsigned short u; __builtin_memcpy(&u, &h, 2); return u;
}

// flagged load: f32 buffer if f!=0 else bf16 buffer
__device__ __forceinline__ float ldf(const void* p, size_t i, int f) {
    return f ? ((const float*)p)[i] : b2f(((const bf16*)p)[i]);
}

__device__ __forceinline__ void ld_g2l(const void* g, void* l) {
    __builtin_amdgcn_global_load_lds(
        (const __attribute__((address_space(1))) void*)g,
        (__attribute__((address_space(3))) void*)l,
        16, 0, 0);
}

// ---------------- dtype detection ----------------
__global__ void detect_k(const unsigned short* __restrict__ x, int* __restrict__ flag) {
    int tid = threadIdx.x;
    int cnt = 0;
    for (int i = tid; i < 8192; i += 256) {
        int e = (x[i] >> 7) & 0xFF;
        if (e == 0 || e == 0xFF) cnt++;
    }
    __shared__ int red[256];
    red[tid] = cnt;
    __syncthreads();
    for (int s = 128; s > 0; s >>= 1) {
        if (tid < s) red[tid] += red[tid + s];
        __syncthreads();
    }
    if (tid == 0) flag[0] = (red[0] >= 2) ? 1 : 0;
}

__global__ void cvt_k(const void* __restrict__ src, bf16* __restrict__ dst, int n,
                      const int* __restrict__ flag) {
    int f = *flag;
    int i = blockIdx.x * 256 + threadIdx.x;
    if (i < n) dst[i] = f2b(ldf(src, i, f));
}

// merged small-tensor converts (60 blocks)
__global__ void cvt_small(const void* b_enc, const void* Dp, const void* b1, const void* b2,
                          const void* bn_s, const void* bn_b, const void* W_out, const void* b_out,
                          bf16* b_encb, bf16* Db, bf16* b1b, bf16* b2b, bf16* bnsb, bf16* bnbb,
                          bf16* Woutb, bf16* boutb, const int* __restrict__ flag) {
    int f = *flag;
    int blk = blockIdx.x, t = threadIdx.x;
    const void* src; bf16* dst; int base, n;
    if (blk < 1)       { src = b_enc; dst = b_encb; base = blk;      n = 256; }
    else if (blk < 7)  { src = Dp;    dst = Db;     base = blk - 1;  n = 1536; }
    else if (blk < 31) { src = b1;    dst = b1b;    base = blk - 7;  n = 6144; }
    else if (blk < 37) { src = b2;    dst = b2b;    base = blk - 31; n = 1536; }
    else if (blk < 43) { src = bn_s;  dst = bnsb;   base = blk - 37; n = 1536; }
    else if (blk < 49) { src = bn_b;  dst = bnbb;   base = blk - 43; n = 1536; }
    else if (blk < 59) { src = W_out; dst = Woutb;  base = blk - 49; n = 2560; }
    else               { src = b_out; dst = boutb;  base = 0;        n = 10; }
    int i = base * 256 + t;
    if (i < n) dst[i] = f2b(ldf(src, i, f));
}

__global__ void lamgam_k(const void* __restrict__ nu, const void* __restrict__ th,
                         float* __restrict__ lamb, float* __restrict__ gamt,
                         const int* __restrict__ flag) {
    int f = *flag;
    int g = blockIdx.x * 256 + threadIdx.x;  // 1536
    float nl = ldf(nu, g, f), tl = ldf(th, g, f);
    float mag = expf(-expf(nl));
    float ang = expf(tl);
    lamb[g * 2] = mag * cosf(ang);
    lamb[g * 2 + 1] = mag * sinf(ang);
    gamt[g] = sqrtf(fmaxf(1.f - mag * mag, 1e-12f));
}

// =====================================================================
// GEMM out[m,n] = sum_k A[m,k]*W[n,k] (+epilogue). 128x128 tile, BK=32,
// double-buffered LDS (32KB total), counted vmcnt(4) 1-deep prefetch.
// Block mapping: NBN column-siblings of an M-tile land on the same XCD,
// temporally adjacent -> A-tile L2 reuse (proven round 2: FETCH 66->18MB).
// EPI 1: +bias -> outB & outB2, + BN-stats partials      (encoder)
// EPI 2: +Dv[n]*(a[n]*aux+c[n]) -> bf16                  (LRU C-out)
// EPI 5: v+bias+aux[m,n] -> bf16, + BN-stats partials    (W2 + residual)
// EPI 6: +fbias[n] (fp32) -> bf16                        (Bu, BN folded)
// =====================================================================
template<int NBN, int EPI>
__global__ __launch_bounds__(256)
void gemm_bt(const bf16* __restrict__ A, int lda,
             const bf16* __restrict__ W, int K,
             bf16* __restrict__ outB, bf16* __restrict__ outB2, int ldo,
             const bf16* __restrict__ bias,
             const bf16* __restrict__ Dv, const bf16* __restrict__ aux,
             const float* __restrict__ fstats, float* __restrict__ spart)
{
    constexpr int LG = (NBN == 4) ? 2 : 1;
    const int id = blockIdx.x;
    const int xcd = id & 7, q = id >> 3;
    const int bn = q & (NBN - 1);
    const int bm = (q >> LG) * 8 + xcd;

    const int tid = threadIdx.x;
    const int lane = tid & 63, wv = tid >> 6;
    const int wm = wv >> 1, wn = wv & 1;
    const int quad = lane >> 4, cl = lane & 15;

    __shared__ __align__(16) short AsB[2][128 * 32];
    __shared__ __align__(16) short WsB[2][128 * 32];

    const char* Ab = (const char*)A + (size_t)bm * 128 * ((size_t)lda * 2);
    const char* Wb = (const char*)W + (size_t)bn * 128 * ((size_t)K * 2);
    const int ldab = lda * 2, ldwb = K * 2;

    auto stage = [&](int t, int bi) {
        const int kb = t * 64;   // byte offset of k-window
#pragma unroll
        for (int it = 0; it < 2; ++it) {
            int G = it * 256 + tid;
            int r = G >> 2;
            int gl = (G & 3) ^ ((r >> 1) & 3);
            ld_g2l(Ab + (size_t)r * ldab + kb + gl * 16,
                   (char*)AsB[bi] + (it * 4 + wv) * 1024);
            ld_g2l(Wb + (size_t)r * ldwb + kb + gl * 16,
                   (char*)WsB[bi] + (it * 4 + wv) * 1024);
        }
    };

    f4v acc[4][4];
#pragma unroll
    for (int i = 0; i < 4; i++)
#pragma unroll
        for (int j = 0; j < 4; j++) acc[i][j] = (f4v){0.f, 0.f, 0.f, 0.f};

    const int NT = K >> 5;
    stage(0, 0);
#pragma unroll 2
    for (int t = 0; t < NT; ++t) {
        const int cur = t & 1;
        if (t + 1 < NT) {
            stage(t + 1, cur ^ 1);
            asm volatile("s_waitcnt vmcnt(4)" ::: "memory");
        } else {
            asm volatile("s_waitcnt vmcnt(0)" ::: "memory");
        }
        asm volatile("s_barrier" ::: "memory");
        const char* Ac = (const char*)AsB[cur];
        const char* Wc = (const char*)WsB[cur];
        s8v af[4], bf_[4];
#pragma unroll
        for (int i = 0; i < 4; i++) {
            int r = wm * 64 + i * 16 + cl;
            af[i] = *(const s8v*)(Ac + r * 64 + ((quad ^ ((r >> 1) & 3)) * 16));
        }
#pragma unroll
        for (int j = 0; j < 4; j++) {
            int r = wn * 64 + j * 16 + cl;
            bf_[j] = *(const s8v*)(Wc + r * 64 + ((quad ^ ((r >> 1) & 3)) * 16));
        }
#pragma unroll
        for (int i = 0; i < 4; i++)
#pragma unroll
            for (int j = 0; j < 4; j++)
                acc[i][j] = __builtin_amdgcn_mfma_f32_16x16x32_bf16(af[i], bf_[j], acc[i][j], 0, 0, 0);
        asm volatile("s_barrier" ::: "memory");
    }

    const size_t ld = (size_t)ldo;
    constexpr bool STATS = (EPI == 1 || EPI == 5);
    float* sred = (float*)AsB;
#pragma unroll
    for (int j = 0; j < 4; j++) {
        float ss = 0.f, ss2 = 0.f;
        const int n = bn * 128 + wn * 64 + j * 16 + cl;
#pragma unroll
        for (int i = 0; i < 4; i++) {
#pragma unroll
            for (int r4 = 0; r4 < 4; r4++) {
                int m = bm * 128 + wm * 64 + i * 16 + quad * 4 + r4;
                size_t idx = (size_t)m * ld + n;
                float v = acc[i][j][r4];
                if (EPI == 1) {
                    v += b2f(bias[n]);
                    outB[idx] = f2b(v);
                    outB2[idx] = f2b(v);
                } else if (EPI == 2) {
                    v += b2f(Dv[n]) * (fstats[n] * b2f(aux[idx]) + fstats[256 + n]);
                    outB[idx] = f2b(v);
                } else if (EPI == 5) {
                    v += b2f(bias[n]) + b2f(aux[idx]);
                    outB[idx] = f2b(v);
                } else if (EPI == 6) {
                    v += fstats[n];
                    outB[idx] = f2b(v);
                }
                if (STATS) { ss += v; ss2 += v * v; }
            }
        }
        if (STATS) {
            ss += __shfl_xor(ss, 16);  ss += __shfl_xor(ss, 32);
            ss2 += __shfl_xor(ss2, 16); ss2 += __shfl_xor(ss2, 32);
            if (lane < 16) {
                sred[(wv * 4 + j) * 16 + cl] = ss;
                sred[256 + (wv * 4 + j) * 16 + cl] = ss2;
            }
        }
    }
    if constexpr (STATS) {
        asm volatile("s_waitcnt lgkmcnt(0)" ::: "memory");
        asm volatile("s_barrier" ::: "memory");
        if (tid < 128) {
            float sv = sred[tid] + sred[128 + tid];
            float sv2 = sred[256 + tid] + sred[256 + 128 + tid];
            spart[(size_t)bm * 256 + bn * 128 + tid] = sv;
            spart[131072 + (size_t)bm * 256 + bn * 128 + tid] = sv2;
        }
    }
}

// ---------------- fused GLU GEMM (value+gate panels, same structure) -----
__global__ __launch_bounds__(256)
void gemm_glu(const bf16* __restrict__ A, int lda,
              const bf16* __restrict__ W, int K,
              bf16* __restrict__ outB, int ldo,
              const bf16* __restrict__ bias)
{
    const int id = blockIdx.x;
    const int xcd = id & 7, q = id >> 3;
    const int bn = q & 3;
    const int bm = (q >> 2) * 8 + xcd;

    const int tid = threadIdx.x;
    const int lane = tid & 63, wv = tid >> 6;
    const int wm = wv >> 1, wn = wv & 1;
    const int quad = lane >> 4, cl = lane & 15;

    __shared__ __align__(16) short AsB[2][128 * 32];
    __shared__ __align__(16) short WvB[2][128 * 32];
    __shared__ __align__(16) short WgB[2][128 * 32];

    const char* Ab = (const char*)A + (size_t)bm * 128 * ((size_t)lda * 2);
    const char* Wvb = (const char*)W + (size_t)(bn * 128) * ((size_t)K * 2);
    const char* Wgb = (const char*)W + (size_t)(512 + bn * 128) * ((size_t)K * 2);
    const int ldab = lda * 2, ldwb = K * 2;

    auto stage = [&](int t, int bi) {
        const int kb = t * 64;
#pragma unroll
        for (int it = 0; it < 2; ++it) {
            int G = it * 256 + tid;
            int r = G >> 2;
            int gl = (G & 3) ^ ((r >> 1) & 3);
            int loff = (it * 4 + wv) * 1024;
            ld_g2l(Ab  + (size_t)r * ldab + kb + gl * 16, (char*)AsB[bi] + loff);
            ld_g2l(Wvb + (size_t)r * ldwb + kb + gl * 16, (char*)WvB[bi] + loff);
            ld_g2l(Wgb + (size_t)r * ldwb + kb + gl * 16, (char*)WgB[bi] + loff);
        }
    };

    f4v accv[4][4], accg[4][4];
#pragma unroll
    for (int i = 0; i < 4; i++)
#pragma unroll
        for (int j = 0; j < 4; j++) {
            accv[i][j] = (f4v){0.f, 0.f, 0.f, 0.f};
            accg[i][j] = (f4v){0.f, 0.f, 0.f, 0.f};
        }

    const int NT = K >> 5;
    stage(0, 0);
#pragma unroll 2
    for (int t = 0; t < NT; ++t) {
        const int cur = t & 1;
        if (t + 1 < NT) {
            stage(t + 1, cur ^ 1);
            asm volatile("s_waitcnt vmcnt(6)" ::: "memory");
        } else {
            asm volatile("s_waitcnt vmcnt(0)" ::: "memory");
        }
        asm volatile("s_barrier" ::: "memory");
        const char* Ac = (const char*)AsB[cur];
        const char* Vc = (const char*)WvB[cur];
        const char* Gc = (const char*)WgB[cur];
        s8v af[4], bv[4], bg[4];
#pragma unroll
        for (int i = 0; i < 4; i++) {
            int r = wm * 64 + i * 16 + cl;
            af[i] = *(const s8v*)(Ac + r * 64 + ((quad ^ ((r >> 1) & 3)) * 16));
        }
#pragma unroll
        for (int j = 0; j < 4; j++) {
            int r = wn * 64 + j * 16 + cl;
            int off = r * 64 + ((quad ^ ((r >> 1) & 3)) * 16);
            bv[j] = *(const s8v*)(Vc + off);
            bg[j] = *(const s8v*)(Gc + off);
        }
#pragma unroll
        for (int i = 0; i < 4; i++)
#pragma unroll
            for (int j = 0; j < 4; j++)
                accv[i][j] = __builtin_amdgcn_mfma_f32_16x16x32_bf16(af[i], bv[j], accv[i][j], 0, 0, 0);
#pragma unroll
        for (int i = 0; i < 4; i++)
#pragma unroll
            for (int j = 0; j < 4; j++)
                accg[i][j] = __builtin_amdgcn_mfma_f32_16x16x32_bf16(af[i], bg[j], accg[i][j], 0, 0, 0);
        asm volatile("s_barrier" ::: "memory");
    }

    const size_t ld = (size_t)ldo;
#pragma unroll
    for (int i = 0; i < 4; i++) {
#pragma unroll
        for (int j = 0; j < 4; j++) {
#pragma unroll
            for (int r4 = 0; r4 < 4; r4++) {
                int m = bm * 128 + wm * 64 + i * 16 + quad * 4 + r4;
                int n = bn * 128 + wn * 64 + j * 16 + cl;
                float v = accv[i][j][r4] + b2f(bias[n]);
                float g = accg[i][j][r4] + b2f(bias[512 + n]);
                outB[(size_t)m * ld + n] = f2b(v * (1.f / (1.f + expf(-g))));
            }
        }
    }
}

// ---------------- BatchNorm finish: partials -> affine tables -------------
__global__ void bn_finish2(const float* __restrict__ part, float* __restrict__ stats,
                           const bf16* __restrict__ sc, const bf16* __restrict__ bi) {
    int e = blockIdx.x;   // 256
    int t = threadIdx.x;
    float s = part[(size_t)t * 256 + e] + part[(size_t)(t + 256) * 256 + e];
    float s2 = part[131072 + (size_t)t * 256 + e] + part[131072 + (size_t)(t + 256) * 256 + e];
    __shared__ float rs[256], rs2[256];
    rs[t] = s; rs2[t] = s2;
    __syncthreads();
    for (int k = 128; k > 0; k >>= 1) {
        if (t < k) { rs[t] += rs[t + k]; rs2[t] += rs2[t + k]; }
        __syncthreads();
    }
    if (t == 0) {
        float mu = rs[0] * (1.f / 65536.f);
        float var = rs2[0] * (1.f / 65536.f) - mu * mu;
        float a = rsqrtf(var + 1e-5f) * b2f(sc[e]);
        stats[e] = a;
        stats[256 + e] = b2f(bi[e]) - mu * a;
    }
}

// wb[n,e] = B_?[h,e]*gamma[h]*a[e] with INTERLEAVED rows (n=2h -> re, 2h+1 -> im)
// + fused Bu bias: bubias[n] = gamma[h] * sum_e c[e]*B_?[h,e]
__global__ void pack_wb(const void* __restrict__ B_re, const void* __restrict__ B_im,
                        size_t off, const float* __restrict__ gam,
                        const float* __restrict__ stats,
                        bf16* __restrict__ out, float* __restrict__ bias_out,
                        const int* __restrict__ flag) {
    int f = *flag;
    int n = blockIdx.x;   // 512
    int e = threadIdx.x;
    int h = n >> 1;
    const void* src = (n & 1) ? B_im : B_re;
    float v = ldf(src, off + (size_t)h * 256 + e, f);
    out[(size_t)n * 256 + e] = f2b(v * gam[h] * stats[e]);
    __shared__ float rs[256];
    rs[e] = v * stats[256 + e];
    __syncthreads();
    for (int k = 128; k > 0; k >>= 1) {
        if (e < k) rs[e] += rs[e + k];
        __syncthreads();
    }
    if (e == 0) bias_out[n] = rs[0] * gam[h];
}

// wc rows (k interleaved): k=2h -> C_re[e,h], k=2h+1 -> -C_im[e,h]
__global__ void pack_wc(const void* __restrict__ C_re, const void* __restrict__ C_im,
                        size_t off, bf16* __restrict__ out, const int* __restrict__ flag) {
    int f = *flag;
    int g = blockIdx.x * 256 + threadIdx.x;  // 256*512
    int e = g >> 9, k = g & 511, h = k >> 1;
    float v = ldf((k & 1) ? C_im : C_re, off + (size_t)e * 256 + h, f);
    out[g] = f2b((k & 1) ? -v : v);
}

__global__ void pack_w1t(const void* __restrict__ W1, size_t off, bf16* __restrict__ out,
                         const int* __restrict__ flag) {
    int f = *flag;
    int g = blockIdx.x * 256 + threadIdx.x;  // 1024*256
    int n = g >> 8, k = g & 255;
    out[g] = f2b(ldf(W1, off + (size_t)k * 1024 + n, f));
}

__global__ void pack_w2t(const void* __restrict__ W2, size_t off, bf16* __restrict__ out,
                         const int* __restrict__ flag) {
    int f = *flag;
    int g = blockIdx.x * 256 + threadIdx.x;  // 256*512
    int n = g >> 9, k = g & 511;
    out[g] = f2b(ldf(W2, off + (size_t)k * 256 + n, f));
}

// ---------------- LRU scan (interleaved re/im layout) ----------------
// bu: [M,512] bf16, col 2h = re_h, col 2h+1 = im_h. Thread owns h-pair ->
// 8B contiguous load per row (coalescing sweet spot).
__global__ void lru_carry(const bf16* __restrict__ bu, const float* __restrict__ lam,
                          float* __restrict__ carry) {
    int gg = blockIdx.x * 256 + threadIdx.x;  // 65536
    int hp = gg & 127, c = (gg >> 7) & 15, b = gg >> 11;
    f4v lm = *(const f4v*)&lam[hp * 4];       // lr0,li0,lr1,li1
    float sr0 = 0.f, si0 = 0.f, sr1 = 0.f, si1 = 0.f;
    const char* p = (const char*)(bu + ((size_t)(b * TLEN + c * TCH)) * 512) + hp * 8;
    for (int t = 0; t < TCH; t++) {
        unsigned long long u = *(const unsigned long long*)p;
        float ur0 = bits2f((unsigned short)u), ui0 = bits2f((unsigned short)(u >> 16));
        float ur1 = bits2f((unsigned short)(u >> 32)), ui1 = bits2f((unsigned short)(u >> 48));
        float nr0 = lm[0] * sr0 - lm[1] * si0 + ur0;
        si0 = lm[0] * si0 + lm[1] * sr0 + ui0; sr0 = nr0;
        float nr1 = lm[2] * sr1 - lm[3] * si1 + ur1;
        si1 = lm[2] * si1 + lm[3] * sr1 + ui1; sr1 = nr1;
        p += 1024;
    }
    *(f4v*)&carry[(size_t)gg * 4] = (f4v){sr0, si0, sr1, si1};
}

__global__ void lru_prefix(const float* __restrict__ carry, float* __restrict__ pre,
                           const float* __restrict__ lam) {
    int g = blockIdx.x * 256 + threadIdx.x;  // 8192
    int h = g & 255, b = g >> 8;
    float pr = lam[h * 2], pi = lam[h * 2 + 1];  // lam^128 via 7 squarings
    for (int k = 0; k < 7; k++) { float nr = pr * pr - pi * pi; pi = 2.f * pr * pi; pr = nr; }
    float er = 0.f, ei = 0.f;
    for (int c = 0; c < NCHUNK; c++) {
        size_t idx = ((size_t)(b * NCHUNK + c) * 256 + h) * 2;
        pre[idx] = er; pre[idx + 1] = ei;
        float cr = carry[idx], ci = carry[idx + 1];
        float nr = pr * er - pi * ei + cr;
        ei = pr * ei + pi * er + ci;
        er = nr;
    }
}

__global__ void lru_final(bf16* __restrict__ bu, const float* __restrict__ pre,
                          const float* __restrict__ lam) {
    int gg = blockIdx.x * 256 + threadIdx.x;  // 65536
    int hp = gg & 127, c = (gg >> 7) & 15, b = gg >> 11;
    f4v lm = *(const f4v*)&lam[hp * 4];
    f4v st = *(const f4v*)&pre[(size_t)gg * 4];
    float sr0 = st[0], si0 = st[1], sr1 = st[2], si1 = st[3];
    char* p = (char*)(bu + ((size_t)(b * TLEN + c * TCH)) * 512) + hp * 8;
    for (int t = 0; t < TCH; t++) {
        unsigned long long u = *(const unsigned long long*)p;
        float ur0 = bits2f((unsigned short)u), ui0 = bits2f((unsigned short)(u >> 16));
        float ur1 = bits2f((unsigned short)(u >> 32)), ui1 = bits2f((unsigned short)(u >> 48));
        float nr0 = lm[0] * sr0 - lm[1] * si0 + ur0;
        si0 = lm[0] * si0 + lm[1] * sr0 + ui0; sr0 = nr0;
        float nr1 = lm[2] * sr1 - lm[3] * si1 + ur1;
        si1 = lm[2] * si1 + lm[3] * sr1 + ui1; sr1 = nr1;
        unsigned long long w = (unsigned long long)f2bits(sr0)
                             | ((unsigned long long)f2bits(si0) << 16)
                             | ((unsigned long long)f2bits(sr1) << 32)
                             | ((unsigned long long)f2bits(si1) << 48);
        *(unsigned long long*)p = w;
        p += 1024;
    }
}

// ---------------- pooling + head ----------------
__global__ void pool_part(const bf16* __restrict__ xc, float* __restrict__ part) {
    int blk = blockIdx.x;  // 512
    int b = blk >> 4, tc = blk & 15;
    int e = threadIdx.x;
    const bf16* p = xc + ((size_t)b * TLEN + tc * TCH) * 256 + e;
    float s = 0.f;
    for (int r = 0; r < TCH; r++) { s += b2f(*p); p += 256; }
    part[(size_t)blk * 256 + e] = s;
}

__global__ void head_k(const float* __restrict__ part, const bf16* __restrict__ W_out,
                       const bf16* __restrict__ b_out, void* __restrict__ out,
                       const int* __restrict__ flag) {
    int b = blockIdx.x;
    int tid = threadIdx.x;
    __shared__ float sp[256];
    __shared__ float red[160];
    float s = 0.f;
    for (int c = 0; c < 16; c++) s += part[((size_t)(b * 16 + c)) * 256 + tid];
    sp[tid] = s * (1.f / 2048.f);
    __syncthreads();
    if (tid < 160) {
        int o = tid >> 4, sg = tid & 15;
        float a = 0.f;
        for (int e = sg; e < 256; e += 16) a += sp[e] * b2f(W_out[e * 10 + o]);
        red[tid] = a;
    }
    __syncthreads();
    if (tid < 10) {
        float acc = b2f(b_out[tid]);
        for (int sg = 0; sg < 16; sg++) acc += red[tid * 16 + sg];
        if (*flag) ((float*)out)[b * 10 + tid] = acc;
        else       ((bf16*)out)[b * 10 + tid] = f2b(acc);
    }
}

__global__ void pack_wt_enc(const void* __restrict__ W_enc, bf16* __restrict__ out,
                            const int* __restrict__ flag) {
    int f = *flag;
    int g = blockIdx.x * 256 + threadIdx.x;  // 16384
    int n = g >> 6, k = g & 63;
    out[g] = f2b(ldf(W_enc, (size_t)k * 256 + n, f));
}

extern "C" void kernel_launch(void* const* d_in, const int* in_sizes, int n_in,
                              void* d_out, int out_size, void* d_ws, size_t ws_size,
                              hipStream_t stream) {
    (void)in_sizes; (void)n_in; (void)out_size; (void)ws_size;
    const void* x      = d_in[0];
    const void* W_enc  = d_in[1];
    const void* b_enc  = d_in[2];
    const void* nu_log = d_in[3];
    const void* th_log = d_in[4];
    const void* B_re   = d_in[5];
    const void* B_im   = d_in[6];
    const void* C_re   = d_in[7];
    const void* C_im   = d_in[8];
    const void* Dp     = d_in[9];
    const void* W1     = d_in[10];
    const void* b1     = d_in[11];
    const void* W2     = d_in[12];
    const void* b2     = d_in[13];
    const void* bn_s   = d_in[14];
    const void* bn_b   = d_in[15];
    const void* W_out  = d_in[16];
    const void* b_out  = d_in[17];

    // workspace layout (~173 MB)
    char* w = (char*)d_ws;
    bf16* xc  = (bf16*)w; w += (size_t)MTOT * 256 * 2;   // residual stream
    bf16* y   = (bf16*)w; w += (size_t)MTOT * 256 * 2;   // residual anchor
    bf16* hbn = (bf16*)w; w += (size_t)MTOT * 256 * 2;   // LRU out
    bf16* bu  = (bf16*)w; w += (size_t)MTOT * 512 * 2;   // Bu/hs (interleaved), GLU out
    float* stats  = (float*)w; w += 4096;                // a[256], c[256]
    float* bnpart = (float*)w; w += 1048576;             // stats partials
    float* carry  = (float*)w; w += 1048576;
    float* pre    = (float*)w; w += 1048576;
    float* part   = (float*)w; w += 524288;
    float* lamb   = (float*)w; w += 12288;               // 1536*2 fp32
    float* gamt   = (float*)w; w += 6144;                // 1536 fp32
    float* bubias = (float*)w; w += 2048;                // 512 fp32
    int*   flag   = (int*)w;  w += 256;
    bf16* wt_enc = (bf16*)w; w += 32768;
    bf16* wb  = (bf16*)w; w += 262144;
    bf16* wc  = (bf16*)w; w += 262144;
    bf16* w1t = (bf16*)w; w += 524288;
    bf16* w2t = (bf16*)w; w += 262144;
    bf16* b_encb = (bf16*)w; w += 512;
    bf16* Db     = (bf16*)w; w += 3072;
    bf16* b1b    = (bf16*)w; w += 12288;
    bf16* b2b    = (bf16*)w; w += 3072;
    bf16* bnsb   = (bf16*)w; w += 3072;
    bf16* bnbb   = (bf16*)w; w += 3072;
    bf16* Woutb  = (bf16*)w; w += 5120;
    bf16* boutb  = (bf16*)w; w += 32;
    bf16* xb = bu;  // x's bf16 copy aliases bu (dead until first Bu GEMM)

    dim3 blk(256);
    detect_k<<<1, blk, 0, stream>>>((const unsigned short*)x, flag);
    cvt_k<<<16384, blk, 0, stream>>>(x, xb, 4194304, flag);
    cvt_small<<<60, blk, 0, stream>>>(b_enc, Dp, b1, b2, bn_s, bn_b, W_out, b_out,
                                      b_encb, Db, b1b, b2b, bnsb, bnbb, Woutb, boutb, flag);
    lamgam_k<<<6, blk, 0, stream>>>(nu_log, th_log, lamb, gamt, flag);
    pack_wt_enc<<<64, blk, 0, stream>>>(W_enc, wt_enc, flag);

    // encoder: [M,64] @ W_enc^T + b_enc -> xc and y (+ BN stats partials)
    gemm_bt<2, 1><<<1024, blk, 0, stream>>>(xb, 64, wt_enc, 64, xc, y, 256,
                                            b_encb, nullptr, nullptr, nullptr, bnpart);
    for (int i = 0; i < 6; ++i) {
        bn_finish2<<<256, blk, 0, stream>>>(bnpart, stats, bnsb + i * 256, bnbb + i * 256);
        pack_wb<<<512, blk, 0, stream>>>(B_re, B_im, (size_t)i * 65536, gamt + i * 256,
                                         stats, wb, bubias, flag);
        // Bu = BN(xc) @ (gamma*[B;B])^T, interleaved cols -> bu [M,512]
        gemm_bt<4, 6><<<2048, blk, 0, stream>>>(xc, 256, wb, 256, bu, nullptr, 512,
                                                nullptr, nullptr, nullptr, bubias, nullptr);
        lru_carry<<<256, blk, 0, stream>>>(bu, lamb + i * 512, carry);
        lru_prefix<<<32, blk, 0, stream>>>(carry, pre, lamb + i * 512);
        lru_final<<<256, blk, 0, stream>>>(bu, pre, lamb + i * 512);
        pack_wc<<<512, blk, 0, stream>>>(C_re, C_im, (size_t)i * 65536, wc, flag);
        // lru_out = hs @ [C_re;-C_im]^T + D*(a*xc+c) -> hbn [M,256]
        gemm_bt<2, 2><<<1024, blk, 0, stream>>>(bu, 512, wc, 512, hbn, nullptr, 256,
                                                nullptr, Db + i * 256, xc, stats, nullptr);
        pack_w1t<<<1024, blk, 0, stream>>>(W1, (size_t)i * 262144, w1t, flag);
        // fused GLU MLP: bu = (hbn@W1v+b1v)*sigmoid(hbn@W1g+b1g)  [M,512]
        gemm_glu<<<2048, blk, 0, stream>>>(hbn, 256, w1t, 256, bu, 512, b1b + i * 1024);
        pack_w2t<<<512, blk, 0, stream>>>(W2, (size_t)i * 131072, w2t, flag);
        // xc = glu @ W2^T + b2 + y (+ BN stats partials for next layer)
        gemm_bt<2, 5><<<1024, blk, 0, stream>>>(bu, 512, w2t, 512, xc, nullptr, 256,
                                                b2b + i * 256, nullptr, y, nullptr, bnpart);
    }
    pool_part<<<512, blk, 0, stream>>>(xc, part);
    head_k<<<32, blk, 0, stream>>>(part, Woutb, boutb, d_out, flag);
}